// Round 7
// baseline (38.312 us; speedup 1.0000x reference)
//
#include <hip/hip_runtime.h>

// CompressImageGPU: bilinear down(0.5, antialias) -> up -> +8x8 block noise -> clip,
// composed into one separable 6-tap conv on x.
// Round 7: TY=16 full-width tiles, 1024-thread blocks (8 row slots), LDS 44KB ->
// exactly 2 blocks/CU = 32 waves = 100% occupancy; __launch_bounds__(1024,8)
// caps VGPR at 64 so both blocks stay resident while allowing a real 2-deep
// load pipeline (R6's VGPR=24 serialized it). NT stores, XCD-chunked swizzle.

typedef float f32x4 __attribute__((ext_vector_type(4)));

namespace {
constexpr int IMG = 512;
constexpr int TY = 16;          // output rows per block
constexpr int HROWS = TY + 6;   // 22
constexpr float I32 = 1.0f / 32.0f;
constexpr float I7  = 1.0f / 7.0f;
constexpr float I28 = 1.0f / 28.0f;
}

__device__ __forceinline__ f32x4 vfma(float w, f32x4 a, f32x4 acc) {
  acc.x = fmaf(w, a.x, acc.x); acc.y = fmaf(w, a.y, acc.y);
  acc.z = fmaf(w, a.z, acc.z); acc.w = fmaf(w, a.w, acc.w);
  return acc;
}
__device__ __forceinline__ f32x4 vmul(float w, f32x4 a) {
  f32x4 r; r.x = w * a.x; r.y = w * a.y; r.z = w * a.z; r.w = w * a.w;
  return r;
}

__global__ __launch_bounds__(1024, 8) void compress_fused7_kernel(
    const float* __restrict__ x, const float* __restrict__ bn,
    float* __restrict__ out) {
  // XCD-chunked bijective swizzle (nwg = 3072, divisible by 8).
  const int nwg = gridDim.x;
  const int cpx = nwg >> 3;
  const int bid = blockIdx.x;
  const int logical = (bid & 7) * cpx + (bid >> 3);
  const int ty = logical & 31;      // y-tile 0..31
  const int plane = logical >> 5;   // 0..95
  const int b = plane / 3;
  const int y0 = ty * TY;
  const int tid = threadIdx.x;
  const int cg = tid & 127;         // column group: cols 4cg..4cg+3
  const int rs = tid >> 7;          // row slot 0..7 (uniform per wave)
  const int gx0 = 4 * cg;

  __shared__ float H[HROWS][IMG];   // 44 KB

  const float* xp = x + (size_t)plane * (IMG * IMG);
  float* op = out + (size_t)plane * (IMG * IMG);

  // per-thread noise value: rows (y0+2rs, y0+2rs+1) share one 8-row band
  const float nzv =
      (bn[(size_t)b * 4096 + ((y0 + 2 * rs) >> 3) * 64 + (cg >> 1)] - 0.5f) * 0.02f;

  const bool left  = (cg == 0);
  const bool right = (cg == 127);
  const int A0 = left ? 0 : (right ? IMG - 12 : gx0 - 4);  // f[i] = x[A0+i]

  auto rowptr = [&](int r) -> const f32x4* {
    int g = y0 - 3 + r;
    g = max(0, min(IMG - 1, g));
    return (const f32x4*)(xp + (size_t)g * IMG + A0);
  };

  auto hconv = [&](f32x4 qa, f32x4 qb, f32x4 qc) -> f32x4 {
    const float f0 = qa.x, f1 = qa.y, f2 = qa.z, f3 = qa.w;
    const float f4_ = qb.x, f5 = qb.y, f6 = qb.z, f7 = qb.w;
    const float f8 = qc.x, f9 = qc.y, f10 = qc.z, f11 = qc.w;
    f32x4 h;
    if (left) {  // f[i] = x[i]
      h.x = (3.f * f0 + 3.f * f1 + f2) * I7;
      h.y = 9*I28*f0 + (9*I28 + I32)*f1 + (3*I28 + 3*I32)*f2 + 3*I32*f3 + I32*f4_;
      h.z = 3*I28*f0 + (3*I28 + 3*I32)*f1 + (I28 + 9*I32)*f2 + 9*I32*f3 + 3*I32*f4_;
      h.w = (3.f*f1 + 9.f*f2 + 10.f*f3 + 6.f*f4_ + 3.f*f5 + f6) * I32;
    } else if (right) {  // f[i] = x[500+i]
      h.x = (f5 + 3.f*f6 + 6.f*f7 + 10.f*f8 + 9.f*f9 + 3.f*f10) * I32;
      h.y = 3*I32*f7 + 9*I32*f8 + (I28 + 9*I32)*f9 + (3*I28 + 3*I32)*f10 + 3*I28*f11;
      h.z = I32*f7 + 3*I32*f8 + (3*I28 + 3*I32)*f9 + (9*I28 + I32)*f10 + 9*I28*f11;
      h.w = (f9 + 3.f*f10 + 3.f*f11) * I7;
    } else {  // f[i] = x[gx0-4+i]
      h.x = (f1 + 3.f*f2 + 6.f*f3 + 10.f*f4_ + 9.f*f5 + 3.f*f6) * I32;
      h.y = (3.f*f3 + 9.f*f4_ + 10.f*f5 + 6.f*f6 + 3.f*f7 + f8) * I32;
      h.z = (f3 + 3.f*f4_ + 6.f*f5 + 10.f*f6 + 9.f*f7 + 3.f*f8) * I32;
      h.w = (3.f*f5 + 9.f*f6 + 10.f*f7 + 6.f*f8 + 3.f*f9 + f10) * I32;
    }
    return h;
  };

  // ---- h-pass: rows rs, rs+8, rs+16 (last only if rs<6); 2-deep pipeline ----
  const bool has2 = (rs < 6);
  const f32x4* p0 = rowptr(rs);
  const f32x4* p1 = rowptr(rs + 8);
  f32x4 a0 = p0[0], b0 = p0[1], c0 = p0[2];
  f32x4 a1 = p1[0], b1 = p1[1], c1 = p1[2];

  *(f32x4*)&H[rs][gx0] = hconv(a0, b0, c0);

  f32x4 a2, b2, c2;
  if (has2) { const f32x4* p2 = rowptr(rs + 16); a2 = p2[0]; b2 = p2[1]; c2 = p2[2]; }

  *(f32x4*)&H[rs + 8][gx0] = hconv(a1, b1, c1);
  if (has2) *(f32x4*)&H[rs + 16][gx0] = hconv(a2, b2, c2);
  __syncthreads();

  // ---- v-pass: 2 consecutive output rows (even,odd) from 8-row window ----
  const int wb = 2 * rs;  // H rows wb..wb+7; even row taps q0..q5, odd q2..q7
  const bool top = (y0 == 0);
  const bool bot = (y0 == IMG - TY);
  const int gy0 = y0 + 2 * rs;

#define LDQ(j) (*(const f32x4*)&H[wb + (j)][gx0])
  const f32x4 q0 = LDQ(0), q1 = LDQ(1), q2 = LDQ(2), q3 = LDQ(3);
  const f32x4 q4 = LDQ(4), q5 = LDQ(5), q6 = LDQ(6), q7 = LDQ(7);
#undef LDQ

  f32x4 oE, oO;
  if (top && rs == 0) {
    // gy=0: (3,3,1)/7 on x-rows 0,1,2 -> q3..q5 (H[0..3] all = row 0)
    oE = vfma(3*I7, q3, vfma(3*I7, q4, vmul(I7, q5)));
    // gy=1: rows 0..4 -> q3..q7
    oO = vfma(9*I28, q3, vfma(9*I28 + I32, q4,
         vfma(3*I28 + 3*I32, q5, vfma(3*I32, q6, vmul(I32, q7)))));
  } else if (top && rs == 1) {
    // gy=2: rows 0..4 -> q1..q5
    oE = vfma(3*I28, q1, vfma(3*I28 + 3*I32, q2,
         vfma(I28 + 9*I32, q3, vfma(9*I32, q4, vmul(3*I32, q5)))));
    // gy=3: interior odd
    oO = vfma(3*I32, q2, vfma(9*I32, q3, vfma(10*I32, q4,
         vfma(6*I32, q5, vfma(3*I32, q6, vmul(I32, q7))))));
  } else if (bot && rs == 6) {
    // gy=508: interior even
    oE = vfma(I32, q0, vfma(3*I32, q1, vfma(6*I32, q2,
         vfma(10*I32, q3, vfma(9*I32, q4, vmul(3*I32, q5))))));
    // gy=509: rows 507..511 -> q2..q6
    oO = vfma(3*I32, q2, vfma(9*I32, q3, vfma(I28 + 9*I32, q4,
         vfma(3*I28 + 3*I32, q5, vmul(3*I28, q6)))));
  } else if (bot && rs == 7) {
    // gy=510: rows 507..511 -> q0..q4
    oE = vfma(I32, q0, vfma(3*I32, q1, vfma(3*I28 + 3*I32, q2,
         vfma(9*I28 + I32, q3, vmul(9*I28, q4)))));
    // gy=511: rows 509..511 -> q2..q4
    oO = vfma(I7, q2, vfma(3*I7, q3, vmul(3*I7, q4)));
  } else {
    oE = vfma(I32, q0, vfma(3*I32, q1, vfma(6*I32, q2,
         vfma(10*I32, q3, vfma(9*I32, q4, vmul(3*I32, q5))))));
    oO = vfma(3*I32, q2, vfma(9*I32, q3, vfma(10*I32, q4,
         vfma(6*I32, q5, vfma(3*I32, q6, vmul(I32, q7))))));
  }

#define FINISH_STORE(o, ii)                                                    \
  {                                                                            \
    f32x4 v = o;                                                               \
    v.x = fminf(1.f, fmaxf(-1.f, v.x + nzv));                                  \
    v.y = fminf(1.f, fmaxf(-1.f, v.y + nzv));                                  \
    v.z = fminf(1.f, fmaxf(-1.f, v.z + nzv));                                  \
    v.w = fminf(1.f, fmaxf(-1.f, v.w + nzv));                                  \
    __builtin_nontemporal_store(v, (f32x4*)(op + (size_t)(gy0 + ii) * IMG + gx0)); \
  }
  FINISH_STORE(oE, 0)
  FINISH_STORE(oO, 1)
#undef FINISH_STORE
}

extern "C" void kernel_launch(void* const* d_in, const int* in_sizes, int n_in,
                              void* d_out, int out_size, void* d_ws, size_t ws_size,
                              hipStream_t stream) {
  const float* x  = (const float*)d_in[0];
  const float* bn = (const float*)d_in[1];
  float* out = (float*)d_out;

  const int n_planes = in_sizes[0] / (IMG * IMG);  // B*C = 96
  const int nwg = (IMG / TY) * n_planes;           // 32 * 96 = 3072 (div by 8)
  compress_fused7_kernel<<<dim3(nwg), dim3(1024), 0, stream>>>(x, bn, out);
}